// Round 1
// 285.069 us; speedup vs baseline: 1.0149x; 1.0149x over previous
//
#include <hip/hip_runtime.h>
#include <hip/hip_fp16.h>
#include <stdint.h>

#define BB      16
#define HH      32
#define HKVN    8
#define GG      4
#define DD      128
#define BLK     256
#define MAXBLKN 16
#define MAXCTXN 4096
#define NSLOTSN 65536
#define ATT_SCALE 0.08838834764831845f
#define QEPS    1e-8f

#define NSPLIT  16
#define CHUNK   256    // tokens per attention partial block (= 1 kv block)

// output layout (all float32, concatenated in reference return order)
#define O_OFF   0
#define KC_OFF  65536
#define VC_OFF  (65536 + 67108864)
#define KSC_OFF (65536 + 2*67108864)
#define VSC_OFF (65536 + 2*67108864 + 524288)

// ws layout (floats): M[128][4][16], L[128][4][16], O[128][4][16][128]
#define WS_M    0
#define WS_L    8192
#define WS_O    16384

#define NATT    (BB * HKVN * NSPLIT)   // 2048 attention blocks
#define NCOPY   4096                   // copy blocks
#define NFUSED  (NATT + NCOPY)         // 6144, interleaved 1 attn : 2 copy

typedef float f32x4 __attribute__((ext_vector_type(4)));

// ---------------------------------------------------------------------------
// Fused kernel: attention partials + cache materialization in ONE dispatch.
// The two workloads are independent (both read-only on the caches; disjoint
// writes: ws vs out). Serializing them on the stream left the copy's BW idle
// while the latency-bound attention gather ran. Interleaving 1:2 keeps both
// resident so the attention critical path hides under the streaming copy,
// and attention's gathered reads hit L2/LLC lines the copy sweep just pulled.
// ---------------------------------------------------------------------------
__global__ __launch_bounds__(256) void fused_kernel(
    const float* __restrict__ q,
    const int* __restrict__ k_cache, const int* __restrict__ v_cache,
    const float* __restrict__ k_scale, const float* __restrict__ v_scale,
    const int* __restrict__ block_table, const int* __restrict__ context_lens,
    float* __restrict__ ws, float* __restrict__ out) {
  const int bid = blockIdx.x;
  const int tid = threadIdx.x;

  __shared__ __align__(16) float q_s[GG][DD];
  __shared__ __half p_s[GG][CHUNK];
  __shared__ float racc[8][32][17];    // +1 pad: conflict-free 8-way reduce
  __shared__ float red[GG][4];

  if (bid % 3 != 0) {
    // ================= copy: int32->f32 + scale copy =================
    // Nontemporal stores: 516MB output stream has no reuse; keep L2/LLC
    // free for the int8 cache lines attention re-reads.
    const int cid = bid - (bid / 3 + 1);       // 0..NCOPY-1
    const int NU = 16777216;  // int4 units per cache (67108864 ints / 4)
    const int NS = 131072;    // float4 units per scale cache (524288 / 4)
    const int TOT = 2 * NU + 2 * NS;
    const int stride = NCOPY * 256;
    for (int u = cid * 256 + tid; u < TOT; u += stride) {
      if (u < 2 * NU) {
        bool isK = u < NU;
        int uu = isK ? u : u - NU;
        int4 w = ((const int4*)(isK ? k_cache : v_cache))[uu];
        f32x4 f;
        f.x = (float)w.x; f.y = (float)w.y; f.z = (float)w.z; f.w = (float)w.w;
        __builtin_nontemporal_store(f, (f32x4*)(out + (isK ? KC_OFF : VC_OFF) + uu * 4));
      } else {
        int uu = u - 2 * NU;
        bool isK = uu < NS;
        int vv = isK ? uu : uu - NS;
        float4 w0 = ((const float4*)(isK ? k_scale : v_scale))[vv];
        f32x4 w;
        w.x = w0.x; w.y = w0.y; w.z = w0.z; w.w = w0.w;
        __builtin_nontemporal_store(w, (f32x4*)(out + (isK ? KSC_OFF : VSC_OFF)) + vv);
      }
    }
    return;
  }

  // ================= attention partial =================
  const int aid = bid / 3;             // 0..2047
  const int split = aid & 15;
  const int bh = aid >> 4;             // 0..127
  const int h = bh & 7;
  const int b = bh >> 3;
  const int ctx = context_lens[b];
  const int start = split * CHUNK;
  if (start >= ctx) return;
  const int n = min(CHUNK, ctx - start);
  const int base = block_table[b * MAXBLKN + split] * BLK;  // slot base
  const int lane = tid & 63;
  const int wid = tid >> 6;
  const int qlane = lane & 3;
  const int quad = lane >> 2;

  for (int i = tid; i < GG * DD; i += 256)
    q_s[i >> 7][i & 127] = q[(b * HH + h * GG + (i >> 7)) * DD + (i & 127)];
  __syncthreads();

  // ---- pass 1: logits, quad-per-token (4 iters of 64 tokens) ----
  float lmax[GG] = {-1e30f, -1e30f, -1e30f, -1e30f};
#pragma unroll
  for (int it = 0; it < 4; ++it) {
    const int tok = it * 64 + wid * 16 + quad;
    const bool active = tok < n;
    const int slot = base + tok;
    float dot[GG] = {0.f, 0.f, 0.f, 0.f};
    if (active) {
      const int4* kr = (const int4*)(k_cache + (h * NSLOTSN + slot) * DD);
#pragma unroll
      for (int kk = 0; kk < 8; ++kk) {
        int4 w = kr[qlane + 4 * kk];
        float k0 = (float)w.x, k1 = (float)w.y, k2 = (float)w.z, k3 = (float)w.w;
        const int c = (qlane + 4 * kk) * 4;
#pragma unroll
        for (int g = 0; g < GG; ++g) {
          float4 qv = *(const float4*)&q_s[g][c];
          dot[g] += qv.x * k0 + qv.y * k1 + qv.z * k2 + qv.w * k3;
        }
      }
    }
    // quad reduce (all 4 lanes end with full row dot)
#pragma unroll
    for (int g = 0; g < GG; ++g) {
      dot[g] += __shfl_xor(dot[g], 1);
      dot[g] += __shfl_xor(dot[g], 2);
    }
    if (active && qlane == 0) {
      float mult = k_scale[h * NSLOTSN + slot] * ATT_SCALE;
#pragma unroll
      for (int g = 0; g < GG; ++g) {
        float l = dot[g] * mult;
        p_s[g][tok] = __float2half(l);
        lmax[g] = fmaxf(lmax[g], l);
      }
    }
  }
#pragma unroll
  for (int g = 0; g < GG; ++g)
    for (int off = 32; off; off >>= 1)
      lmax[g] = fmaxf(lmax[g], __shfl_xor(lmax[g], off));
  if (lane == 0)
#pragma unroll
    for (int g = 0; g < GG; ++g) red[g][wid] = lmax[g];
  __syncthreads();
  float m[GG];
#pragma unroll
  for (int g = 0; g < GG; ++g)
    m[g] = fmaxf(fmaxf(red[g][0], red[g][1]), fmaxf(red[g][2], red[g][3]));

  // ---- pass 2: exp + sum (token-per-thread, single step) ----
  float lsum[GG] = {0.f, 0.f, 0.f, 0.f};
  if (tid < n) {
#pragma unroll
    for (int g = 0; g < GG; ++g) {
      float e = __expf(__half2float(p_s[g][tid]) - m[g]);
      p_s[g][tid] = __float2half(e);
      lsum[g] += e;
    }
  }
#pragma unroll
  for (int g = 0; g < GG; ++g)
    for (int off = 32; off; off >>= 1) lsum[g] += __shfl_xor(lsum[g], off);
  __syncthreads();  // red reuse
  if (lane == 0)
#pragma unroll
    for (int g = 0; g < GG; ++g) red[g][wid] = lsum[g];
  __syncthreads();
  float l[GG];
#pragma unroll
  for (int g = 0; g < GG; ++g)
    l[g] = red[g][0] + red[g][1] + red[g][2] + red[g][3];

  // ---- pass 3: PV. int4 V loads: 32 lanes/row, 8 parallel token groups ----
  const int vlane = tid & 31;          // owns dims 4*vlane .. 4*vlane+3
  const int grp = tid >> 5;            // 0..7 token subset
  float acc[GG][4] = {};
  const int vhb = h * NSLOTSN;
#pragma unroll 4
  for (int i = grp; i < n; i += 8) {
    int slot = base + i;
    float vs = v_scale[vhb + slot];
    int4 w = *(const int4*)(v_cache + (vhb + slot) * DD + 4 * vlane);
    float v0 = (float)w.x * vs, v1 = (float)w.y * vs,
          v2 = (float)w.z * vs, v3 = (float)w.w * vs;
#pragma unroll
    for (int g = 0; g < GG; ++g) {
      float p = __half2float(p_s[g][i]);
      acc[g][0] += p * v0; acc[g][1] += p * v1;
      acc[g][2] += p * v2; acc[g][3] += p * v3;
    }
  }
#pragma unroll
  for (int g = 0; g < GG; ++g)
#pragma unroll
    for (int j = 0; j < 4; ++j)
      racc[grp][vlane][g * 4 + j] = acc[g][j];
  __syncthreads();
  // 512 outputs (4 g x 128 d); 256 threads -> 2 each; 8-way sum from LDS
  for (int oidx = tid; oidx < 512; oidx += 256) {
    int gj = oidx & 15;
    int vl = oidx >> 4;
    float s = 0.f;
#pragma unroll
    for (int r = 0; r < 8; ++r) s += racc[r][vl][gj];
    int g = gj >> 2, j = gj & 3;
    ws[WS_O + (((bh * GG + g) * NSPLIT + split) * DD) + (vl * 4 + j)] = s;
  }
  if (tid == 0) {
#pragma unroll
    for (int g = 0; g < GG; ++g) {
      ws[WS_M + (bh * GG + g) * NSPLIT + split] = m[g];
      ws[WS_L + (bh * GG + g) * NSPLIT + split] = l[g];
    }
  }
}

// ---------------------------------------------------------------------------
// Kernel 2: blockIdx.x<128 -> combine partials (+current token); else
// quantize+store current k/v. 128 threads each.
// ---------------------------------------------------------------------------
__global__ __launch_bounds__(128) void finish_kernel(
    const float* __restrict__ q, const float* __restrict__ kin,
    const float* __restrict__ vin, const int* __restrict__ slot_mapping,
    const int* __restrict__ context_lens, float* __restrict__ out,
    const float* __restrict__ ws) {
  const int d = threadIdx.x;
  __shared__ float red[DD];
  __shared__ float lcur_s[GG];

  if (blockIdx.x < 128) {
    // ================= combine =================
    const int bh = blockIdx.x;
    const int h = bh & 7;
    const int b = bh >> 3;
    const int ctx = context_lens[b];
    const int nsp = (ctx + CHUNK - 1) / CHUNK;
    if (d < GG) {
      float dc = 0.f;
      const float* qp = q + (b * HH + h * GG + d) * DD;
      const float* kp = kin + (b * HKVN + h) * DD;
      for (int j = 0; j < DD; ++j) dc += qp[j] * kp[j];
      lcur_s[d] = dc * ATT_SCALE;
    }
    __syncthreads();
    float vcur = vin[(b * HKVN + h) * DD + d];
#pragma unroll
    for (int g = 0; g < GG; ++g) {
      float lc = lcur_s[g];
      float M = lc;
      for (int s = 0; s < nsp; ++s)
        M = fmaxf(M, ws[WS_M + (bh * GG + g) * NSPLIT + s]);
      float denom = __expf(lc - M);
      float o = denom * vcur;
      for (int s = 0; s < nsp; ++s) {
        float w = __expf(ws[WS_M + (bh * GG + g) * NSPLIT + s] - M);
        denom += ws[WS_L + (bh * GG + g) * NSPLIT + s] * w;
        o += ws[WS_O + ((bh * GG + g) * NSPLIT + s) * DD + d] * w;
      }
      out[O_OFF + (b * HH + h * GG + g) * DD + d] = o / denom;
    }
  } else {
    // ================= store-quant =================
    const int sid = blockIdx.x - 128;
    const int b = sid >> 3;
    const int h = sid & 7;
    const int slot = slot_mapping[b];
    for (int b2 = b + 1; b2 < BB; ++b2)
      if (slot_mapping[b2] == slot) return;  // numpy last-wins

    // K
    float xk = kin[(b * HKVN + h) * DD + d];
    red[d] = fabsf(xk);
    __syncthreads();
    for (int off = 64; off; off >>= 1) {
      if (d < off) red[d] = fmaxf(red[d], red[d + off]);
      __syncthreads();
    }
    float sk = fmaxf(red[0] / 127.0f, QEPS);
    __syncthreads();
    float qk = fminf(fmaxf(rintf(xk / sk), -127.0f), 127.0f);
    out[KC_OFF + (h * NSLOTSN + slot) * DD + d] = qk;
    if (d == 0) out[KSC_OFF + h * NSLOTSN + slot] = sk;

    // V
    float xv = vin[(b * HKVN + h) * DD + d];
    red[d] = fabsf(xv);
    __syncthreads();
    for (int off = 64; off; off >>= 1) {
      if (d < off) red[d] = fmaxf(red[d], red[d + off]);
      __syncthreads();
    }
    float sv = fmaxf(red[0] / 127.0f, QEPS);
    float qv = fminf(fmaxf(rintf(xv / sv), -127.0f), 127.0f);
    out[VC_OFF + (h * NSLOTSN + slot) * DD + d] = qv;
    if (d == 0) out[VSC_OFF + h * NSLOTSN + slot] = sv;
  }
}

extern "C" void kernel_launch(void* const* d_in, const int* in_sizes, int n_in,
                              void* d_out, int out_size, void* d_ws, size_t ws_size,
                              hipStream_t stream) {
  const float* q = (const float*)d_in[0];
  const float* k = (const float*)d_in[1];
  const float* v = (const float*)d_in[2];
  const int* k_cache = (const int*)d_in[3];
  const int* v_cache = (const int*)d_in[4];
  const float* k_scale = (const float*)d_in[5];
  const float* v_scale = (const float*)d_in[6];
  const int* slot_mapping = (const int*)d_in[7];
  const int* block_table = (const int*)d_in[8];
  const int* context_lens = (const int*)d_in[9];
  float* out = (float*)d_out;
  float* ws = (float*)d_ws;

  hipLaunchKernelGGL(fused_kernel, dim3(NFUSED), dim3(256), 0, stream,
                     q, k_cache, v_cache, k_scale, v_scale,
                     block_table, context_lens, ws, out);
  hipLaunchKernelGGL(finish_kernel, dim3(256), dim3(128), 0, stream,
                     q, k, v, slot_mapping, context_lens, out, ws);
}